// Round 9
// baseline (4226.534 us; speedup 1.0000x reference)
//
#include <hip/hip_runtime.h>
#include <hip/hip_fp16.h>

typedef _Float16 f16;
typedef _Float16 f16x8 __attribute__((ext_vector_type(8)));
typedef _Float16 f16x4 __attribute__((ext_vector_type(4)));
typedef float    f32x4 __attribute__((ext_vector_type(4)));
typedef unsigned long long u64;

#define TT 512
#define BB 256
#define HH 256

// ---- workspace byte offsets ----
#define O_WFRAG_ENC 0u
#define O_WFRAG_M   393216u
#define O_WFRAG_P   786432u
#define O_WFRAG_GI  1179648u
#define O_HE_ST     1966080u
#define O_HM_ST     2097152u
#define O_HP_ST     2228224u
#define O_HPSUM     2359296u
#define O_XCHG      2621440u   // 3 recs *16 bt *4 q *2 parity *2048 B = 786432
#define O_FLAGS     3407872u   // 192 ints, padded to 1024
#define O_DYN       3408896u
#define DYN_PER_STEP 917504u   // he_buf 131072 + gi_buf 786432 per step

__device__ __forceinline__ float sigf(float x){ return 1.0f/(1.0f+__expf(-x)); }
__device__ __forceinline__ float tanh_(float x){
  float xc = fminf(fmaxf(x,-15.f),15.f);
  float e  = __expf(2.f*xc);
  return (e-1.f)/(e+1.f);
}
// XOR-swizzled element index into a [16][256] f16 tile (16B granules ^ row&7).
// NOTE: granule-XOR with row&7 stays within each 8-granule (=128B) group, so
// j-quarter q always occupies bytes [row*512 + q*128, +128) -- contiguous slab.
__device__ __forceinline__ int hswz(int row, int j){
  return row*256 + ((((j>>3) ^ (row&7)))<<3) + (j&7);
}
// async global->LDS, 16B per lane (dest = wave-uniform base + lane*16)
__device__ __forceinline__ void gload_lds16(const void* g, void* l){
  __builtin_amdgcn_global_load_lds(
      (const __attribute__((address_space(1))) unsigned int*)g,
      (__attribute__((address_space(3))) unsigned int*)l, 16, 0, 0);
}

// =====================================================================
// PREP: weights -> f16 fragment buffers, init states, zero group flags
// =====================================================================
__global__ void prep_kernel(
    const float* __restrict__ enc_whh, const float* __restrict__ mdec_whh,
    const float* __restrict__ pdec_whh, const float* __restrict__ mdec_wih,
    const float* __restrict__ pdec_wih,
    const float* __restrict__ h0e, const float* __restrict__ h0m, const float* __restrict__ h0p,
    f16* __restrict__ wfrag_enc, f16* __restrict__ wfrag_m, f16* __restrict__ wfrag_p,
    f16* __restrict__ wfrag_gi,
    f16* __restrict__ he_st, f16* __restrict__ hm_st, f16* __restrict__ hp_st,
    float* __restrict__ hpsum, int* __restrict__ flags)
{
  int idx = blockIdx.x*256 + threadIdx.x;
  const int NW = 16*3*8*64*8; // 196608
  if (idx < 3*NW){
    int b = idx / NW, e = idx % NW;
    int jj = e & 7, l = (e>>3)&63, ks = (e>>9)&7, t2 = e>>12;
    int g = t2 % 3, w = t2 / 3;
    int row = g*256 + w*16 + (l&15);
    int col = ks*32 + (l>>4)*8 + jj;
    const float* W = (b==0)?enc_whh:((b==1)?mdec_whh:pdec_whh);
    f16* D = (b==0)?wfrag_enc:((b==1)?wfrag_m:wfrag_p);
    D[e] = (f16)W[row*256+col];
    return;
  }
  idx -= 3*NW;
  const int NG = 96*8*64*8; // 393216
  if (idx < NG){
    int e = idx;
    int jj = e&7, l=(e>>3)&63, ks=(e>>9)&7, mt = e>>12;
    int row = mt*16 + (l&15);
    int col = ks*32 + (l>>4)*8 + jj;
    float v = (row < 768) ? mdec_wih[row*256+col] : pdec_wih[(row-768)*256+col];
    wfrag_gi[e] = (f16)v;
    return;
  }
  idx -= NG;
  if (idx < 65536){
    he_st[idx] = (f16)h0e[idx];
    hm_st[idx] = (f16)h0m[idx];
    hp_st[idx] = (f16)h0p[idx];
    hpsum[idx] = 0.f;
    if (idx < 192) flags[idx] = 0;
  }
}

// =====================================================================
// Recurrence core. MODE 0=encoder, 1=mask-dec, 2=pred-dec.
// 4 WGs per (rec, bt), each 256 threads (4 waves). WG q owns j-quarter
// [q*64, q*64+64): its 98 KB slice of W_hh lives in LDS (fragment-ordered,
// ds_read_b128 per MFMA). Full h double-buffered in LDS; h-quarters are
// exchanged through L2 each step with agent-scope atomics + monotone flags.
// Working set ~60 VGPRs -> no spill possible (the r1-r8 killer).
// =====================================================================
template<int MODE>
__device__ __forceinline__ void gru_run(
  int q, int bt, int slice, int SL,
  const f16* __restrict__ wfrag,
  const float* __restrict__ bih, const float* __restrict__ bhh,
  const float* __restrict__ enc_wih,
  const float* __restrict__ seq, const float* __restrict__ dpad,
  const f16* __restrict__ gi_src,       // pre-offset for (bt, rec); bih folded in
  f16* __restrict__ h_state,
  f16* __restrict__ he_buf,
  const float* __restrict__ mlin_w, const float* __restrict__ mlin_b,
  float* __restrict__ out_mask,
  float* __restrict__ hpsum,
  u64* __restrict__ xchg, int* __restrict__ flags,
  unsigned char* smem)
{
  const int tid = threadIdx.x;       // 256
  const int lane = tid & 63;
  const int wid  = tid >> 6;         // 0..3
  const int l15  = lane & 15;
  const int lhi  = lane >> 4;
  const int bi0  = lhi*4;
  const int b0   = bt*16;
  constexpr int FREC = (MODE==1) ? 0 : ((MODE==2) ? 1 : 2);
  const int jb = q*4 + wid;          // global j-block (0..15)
  const int j  = jb*16 + l15;        // this thread's j

  f16* wlds = (f16*)smem;                         // 98304 B weight quarter
  f16* hbuf = (f16*)(smem + 98304);               // 2 x 8192 B (swizzled)
  float* xb   = (float*)(smem + 98304 + 16384);   // [2][16] (enc)
  float* mlwf = xb + 32;                          // [256] (mdec q0)

  // ---- stage weight quarter into LDS: 24 chunks x 4 KB
  {
    const char* src = (const char*)wfrag + (size_t)q*98304u;
    #pragma unroll
    for (int c=0;c<24;++c){
      gload_lds16(src + c*4096 + wid*1024 + (lane<<4),
                  (char*)wlds + c*4096 + wid*1024);
    }
  }

  // ---- biases (dec: bih folded into gi by gi_kernel)
  float cr, cz, cnh, cni=0.f, wr_=0.f, wz_=0.f, wn_=0.f;
  if (MODE==0){
    cr  = bih[j]     + bhh[j];
    cz  = bih[256+j] + bhh[256+j];
    cnh = bhh[512+j];
    cni = bih[512+j];
    wr_ = enc_wih[j]; wz_ = enc_wih[256+j]; wn_ = enc_wih[512+j];
  } else {
    cr = bhh[j]; cz = bhh[256+j]; cnh = bhh[512+j];
  }
  float mlb = 0.f;
  if (MODE==1 && q==0){ mlwf[tid] = mlin_w[tid]; mlb = mlin_b[0]; }

  // ---- initial FULL h -> hbuf[0]
  for (int jb2=wid; jb2<16; jb2+=4){
    const int j2 = jb2*16 + l15;
    #pragma unroll
    for (int r=0;r<4;++r)
      hbuf[hswz(bi0+r, j2)] = h_state[(size_t)(b0+bi0+r)*256 + j2];
  }
  if (MODE==0 && tid<16){
    const int t = slice*SL;
    xb[tid] = (t==0) ? dpad[b0+tid] : seq[(size_t)(t-1)*BB + b0 + tid];
  }
  __syncthreads();   // also drains weight gload_lds (vmcnt 0 before barrier)

  float psum[4];
  if (MODE==2){
    #pragma unroll
    for (int r=0;r<4;++r) psum[r]=0.f;
  }

  const int gbase = (FREC*16 + bt)*4;
  int* myf = flags + gbase + q;

  for (int ts=0; ts<SL; ++ts){
    const int cur = ts & 1;
    f16* hc = hbuf + cur*4096;
    f16* hn = hbuf + (cur^1)*4096;
    const int gstep = slice*SL + ts;

    // early gi loads (dec) / x prefetch (enc)
    f16x4 gv0, gv1, gv2;
    if (MODE!=0){
      const f16* gts = gi_src + (size_t)ts*393216u;
      gv0 = *(const f16x4*)(gts + ((size_t)(      j))*16 + bi0);
      gv1 = *(const f16x4*)(gts + ((size_t)(256 + j))*16 + bi0);
      gv2 = *(const f16x4*)(gts + ((size_t)(512 + j))*16 + bi0);
    } else if (tid<16 && ts+1<SL){
      xb[(cur^1)*16 + tid] = seq[(size_t)(slice*SL + ts)*BB + b0 + tid];
    }

    // mask for previous step (mdec q0): full h is in hc
    if (MODE==1 && q==0 && ts>0){
      const int mb = tid>>4, jj = tid&15;
      float s = 0.f;
      #pragma unroll
      for (int k=0;k<16;++k){ const int jm = jj + k*16; s += (float)hc[hswz(mb, jm)]*mlwf[jm]; }
      s += __shfl_xor(s,1,64); s += __shfl_xor(s,2,64);
      s += __shfl_xor(s,4,64); s += __shfl_xor(s,8,64);
      if (jj==0) out_mask[(size_t)(slice*SL + ts-1)*BB + b0 + mb] = s + mlb;
    }

    // ---- MFMA: A = h (LDS), B = weight quarter (LDS), own j-block
    f32x4 a0 = {cr,cr,cr,cr};
    f32x4 a1 = {cz,cz,cz,cz};
    f32x4 a2 = {cnh,cnh,cnh,cnh};
    #pragma unroll
    for (int ks=0;ks<8;++ks){
      const f16x8 a  = *(const f16x8*)(hc + l15*256 + ((((ks*4+lhi) ^ (l15&7)))<<3));
      const f16x8 b0f = *(const f16x8*)(wlds + ((size_t)(((wid*3+0)*8)+ks)*64 + lane)*8);
      const f16x8 b1f = *(const f16x8*)(wlds + ((size_t)(((wid*3+1)*8)+ks)*64 + lane)*8);
      const f16x8 b2f = *(const f16x8*)(wlds + ((size_t)(((wid*3+2)*8)+ks)*64 + lane)*8);
      a0 = __builtin_amdgcn_mfma_f32_16x16x32_f16(a, b0f, a0, 0,0,0);
      a1 = __builtin_amdgcn_mfma_f32_16x16x32_f16(a, b1f, a1, 0,0,0);
      a2 = __builtin_amdgcn_mfma_f32_16x16x32_f16(a, b2f, a2, 0,0,0);
    }

    // ---- gates (4 (b,j) elems/thread, own quarter)
    {
      float gir[4], giz[4], gin[4];
      if (MODE==0){
        #pragma unroll
        for (int r=0;r<4;++r){
          const float x = xb[cur*16 + bi0 + r];
          gir[r]=x*wr_; giz[r]=x*wz_; gin[r]=x*wn_ + cni;
        }
      } else {
        #pragma unroll
        for (int r=0;r<4;++r){
          gir[r]=(float)gv0[r]; giz[r]=(float)gv1[r]; gin[r]=(float)gv2[r];
        }
      }
      #pragma unroll
      for (int r=0;r<4;++r){
        const int sz = hswz(bi0+r, j);
        const float hprev = (float)hc[sz];
        const float rr = sigf(gir[r] + a0[r]);
        const float zz = sigf(giz[r] + a1[r]);
        const float nn = tanh_(gin[r] + rr*a2[r]);
        const float h  = (1.f-zz)*nn + zz*hprev;
        hn[sz] = (f16)h;
        if (MODE==0) he_buf[((size_t)ts*BB + (b0+bi0+r))*HH + j] = (f16)h;
        if (MODE==2) psum[r] += h;
      }
    }
    __syncthreads();                                        // A: hn own quarter done

    // ---- pack own quarter slab (16 rows x 128 B) -> xchg
    {
      const int row = tid>>4, o8 = tid&15;
      const u64 v = *(const u64*)((const char*)hn + row*512 + q*128 + o8*8);
      __hip_atomic_store(xchg + ((size_t)((gbase+q)*2 + cur))*256 + tid, v,
                         __ATOMIC_RELAXED, __HIP_MEMORY_SCOPE_AGENT);
    }
    __syncthreads();                                        // B: stores drained
    if (tid==0)
      __hip_atomic_store(myf, gstep+1, __ATOMIC_RELEASE, __HIP_MEMORY_SCOPE_AGENT);
    if (tid<3){
      const int pk = tid + (tid>=q ? 1 : 0);
      int* ptf = flags + gbase + pk;
      while (__hip_atomic_load(ptf, __ATOMIC_ACQUIRE, __HIP_MEMORY_SCOPE_AGENT) < gstep+1)
        __builtin_amdgcn_s_sleep(1);
    }
    __syncthreads();                                        // C: partners ready
    {
      const int row = tid>>4, o8 = tid&15;
      #pragma unroll
      for (int pi=0; pi<3; ++pi){
        const int pk = pi + (pi>=q ? 1 : 0);
        const u64 v = __hip_atomic_load(
            xchg + ((size_t)((gbase+pk)*2 + cur))*256 + tid,
            __ATOMIC_RELAXED, __HIP_MEMORY_SCOPE_AGENT);
        *(u64*)((char*)hn + row*512 + pk*128 + o8*8) = v;
      }
    }
    __syncthreads();                                        // D: hn full
  }

  const f16* hf = hbuf + (SL&1)*4096;
  // final mask row (mdec q0)
  if (MODE==1 && q==0){
    const int mb = tid>>4, jj = tid&15;
    float s = 0.f;
    #pragma unroll
    for (int k=0;k<16;++k){ const int jm = jj + k*16; s += (float)hf[hswz(mb, jm)]*mlwf[jm]; }
    s += __shfl_xor(s,1,64); s += __shfl_xor(s,2,64);
    s += __shfl_xor(s,4,64); s += __shfl_xor(s,8,64);
    if (jj==0) out_mask[(size_t)(slice*SL + SL-1)*BB + b0 + mb] = s + mlb;
  }
  // h_state writeback (own quarter)
  #pragma unroll
  for (int r=0;r<4;++r)
    h_state[(size_t)(b0+bi0+r)*256 + j] = hf[hswz(bi0+r, j)];
  if (MODE==2){
    #pragma unroll
    for (int r=0;r<4;++r){
      const size_t idx = (size_t)(b0+bi0+r)*256 + j;
      hpsum[idx] = hpsum[idx] + psum[r];
    }
  }
}

// 192 blocks: q = bid&3 (j-quarter), pp = bid>>2:
// 0..15 mdec bt, 16..31 pdec bt, 32..47 enc bt.
__global__ __launch_bounds__(256,1) void rec_kernel(
  const float* __restrict__ seq, const float* __restrict__ dpad,
  const float* __restrict__ enc_wih, const float* __restrict__ enc_bih, const float* __restrict__ enc_bhh,
  const float* __restrict__ mdec_bhh, const float* __restrict__ pdec_bhh,
  const float* __restrict__ mlin_w, const float* __restrict__ mlin_b,
  const f16* __restrict__ wfrag_enc, const f16* __restrict__ wfrag_m, const f16* __restrict__ wfrag_p,
  f16* __restrict__ he_st, f16* __restrict__ hm_st, f16* __restrict__ hp_st,
  f16* __restrict__ he_buf, const f16* __restrict__ gi_buf,
  float* __restrict__ hpsum, float* __restrict__ out_mask,
  u64* __restrict__ xchg, int* __restrict__ flags,
  int dec_slice, int enc_slice, int SL)
{
  __shared__ __align__(16) unsigned char smem[98304 + 16384 + 128 + 1024 + 512];
  const int bid = blockIdx.x;
  const int q = bid & 3, pp = bid >> 2;
  if (pp < 16){
    if (dec_slice < 0) return;
    const int bt = pp;
    gru_run<1>(q, bt, dec_slice, SL, wfrag_m, nullptr, mdec_bhh, nullptr, nullptr, nullptr,
               gi_buf + (size_t)bt*1536*16, hm_st, nullptr, mlin_w, mlin_b, out_mask, nullptr,
               xchg, flags, smem);
  } else if (pp < 32){
    if (dec_slice < 0) return;
    const int bt = pp - 16;
    gru_run<2>(q, bt, dec_slice, SL, wfrag_p, nullptr, pdec_bhh, nullptr, nullptr, nullptr,
               gi_buf + ((size_t)bt*1536 + 768)*16, hp_st, nullptr, nullptr, nullptr, nullptr, hpsum,
               xchg, flags, smem);
  } else {
    if (enc_slice < 0) return;
    const int bt = pp - 32;
    gru_run<0>(q, bt, enc_slice, SL, wfrag_enc, enc_bih, enc_bhh, enc_wih, seq, dpad,
               nullptr, he_st, he_buf, nullptr, nullptr, nullptr, nullptr,
               xchg, flags, smem);
  }
}

// =====================================================================
// GI: gi[t][b][n] = he[t][b][:] . w_ih_cat[n][:] + bih_cat[n]
// =====================================================================
__global__ __launch_bounds__(256,4) void gi_kernel(
  const f16* __restrict__ he_buf, const f16* __restrict__ wfrag_gi,
  const float* __restrict__ mdec_bih, const float* __restrict__ pdec_bih,
  f16* __restrict__ gi_buf)
{
  const int ts = blockIdx.x >> 2;
  const int bq = blockIdx.x & 3;
  const int tid = threadIdx.x, lane = tid&63, wid = tid>>6;
  const int l15 = lane&15, lhi = lane>>4;
  __shared__ f16 het[64*264];
  {
    const uint4* src = (const uint4*)(he_buf + ((size_t)ts*BB + bq*64)*HH);
    uint4* dst = (uint4*)het;
    #pragma unroll
    for (int k=0;k<8;++k){
      const int i = tid + k*256;
      dst[(i>>5)*33 + (i&31)] = src[i];
    }
  }
  __syncthreads();
  for (int mi=0; mi<24; ++mi){
    const int mt = wid*24 + mi;
    const int row0 = mt*16 + lhi*4;
    float bb[4];
    #pragma unroll
    for (int r=0;r<4;++r){
      const int rw = row0 + r;
      bb[r] = (rw < 768) ? mdec_bih[rw] : pdec_bih[rw-768];
    }
    f32x4 acc[4] = {{0,0,0,0},{0,0,0,0},{0,0,0,0},{0,0,0,0}};
    #pragma unroll
    for (int ks=0;ks<8;++ks){
      const f16x8 a = *(const f16x8*)(wfrag_gi + ((size_t)(mt*8+ks)*64 + lane)*8);
      #pragma unroll
      for (int bt=0;bt<4;++bt){
        const f16x8 b = *(const f16x8*)(het + (bt*16+l15)*264 + ks*32 + lhi*8);
        acc[bt] = __builtin_amdgcn_mfma_f32_16x16x32_f16(a, b, acc[bt], 0,0,0);
      }
    }
    #pragma unroll
    for (int bt=0;bt<4;++bt){
      const int btg = bq*4 + bt;
      const size_t base = (((size_t)ts*16 + btg)*1536 + (size_t)mt*16 + lhi*4)*16 + l15;
      #pragma unroll
      for (int r=0;r<4;++r) gi_buf[base + (size_t)r*16] = (f16)(acc[bt][r] + bb[r]);
    }
  }
}

// =====================================================================
// PRED: pred[b][p] = (hpsum[b]/512) . plin_w[p] + plin_b[p]
// =====================================================================
__global__ __launch_bounds__(256,1) void pred_kernel(
  const float* __restrict__ hpsum, const float* __restrict__ plin_w,
  const float* __restrict__ plin_b, float* __restrict__ out)
{
  __shared__ float hs[256];
  const int p = threadIdx.x;
  const float bias = plin_b[p];
  for (int bb=0; bb<4; ++bb){
    const int b = blockIdx.x*4 + bb;
    __syncthreads();
    hs[p] = hpsum[(size_t)b*256 + p];
    __syncthreads();
    float acc = 0.f;
    const float4* wrow = (const float4*)(plin_w + (size_t)p*256);
    #pragma unroll 4
    for (int k4=0;k4<64;++k4){
      const float4 w = wrow[k4];
      acc += hs[k4*4+0]*w.x + hs[k4*4+1]*w.y + hs[k4*4+2]*w.z + hs[k4*4+3]*w.w;
    }
    out[131072 + (size_t)b*256 + p] = acc*(1.f/512.f) + bias;
  }
}

// =====================================================================
extern "C" void kernel_launch(void* const* d_in, const int* in_sizes, int n_in,
                              void* d_out, int out_size, void* d_ws, size_t ws_size,
                              hipStream_t stream)
{
  const float* seq      = (const float*)d_in[0];
  const float* dpad     = (const float*)d_in[1];
  const float* h0e      = (const float*)d_in[2];
  const float* h0m      = (const float*)d_in[3];
  const float* h0p      = (const float*)d_in[4];
  const float* enc_wih  = (const float*)d_in[5];
  const float* enc_whh  = (const float*)d_in[6];
  const float* enc_bih  = (const float*)d_in[7];
  const float* enc_bhh  = (const float*)d_in[8];
  const float* mdec_wih = (const float*)d_in[9];
  const float* mdec_whh = (const float*)d_in[10];
  const float* mdec_bih = (const float*)d_in[11];
  const float* mdec_bhh = (const float*)d_in[12];
  const float* mlin_w   = (const float*)d_in[13];
  const float* mlin_b   = (const float*)d_in[14];
  const float* pdec_wih = (const float*)d_in[15];
  const float* pdec_whh = (const float*)d_in[16];
  const float* pdec_bih = (const float*)d_in[17];
  const float* pdec_bhh = (const float*)d_in[18];
  const float* plin_w   = (const float*)d_in[19];
  const float* plin_b   = (const float*)d_in[20];
  float* out = (float*)d_out;

  char* ws = (char*)d_ws;
  f16* wfrag_enc = (f16*)(ws + O_WFRAG_ENC);
  f16* wfrag_m   = (f16*)(ws + O_WFRAG_M);
  f16* wfrag_p   = (f16*)(ws + O_WFRAG_P);
  f16* wfrag_gi  = (f16*)(ws + O_WFRAG_GI);
  f16* he_st     = (f16*)(ws + O_HE_ST);
  f16* hm_st     = (f16*)(ws + O_HM_ST);
  f16* hp_st     = (f16*)(ws + O_HP_ST);
  float* hpsum   = (float*)(ws + O_HPSUM);
  u64* xchg      = (u64*)(ws + O_XCHG);
  int* flags     = (int*)(ws + O_FLAGS);

  int SL = 64;
  while (SL > 1 && (size_t)O_DYN + (size_t)SL*DYN_PER_STEP > ws_size) SL >>= 1;
  const int S = TT / SL;
  f16* he_buf = (f16*)(ws + O_DYN);
  f16* gi_buf = (f16*)(ws + O_DYN + (size_t)SL*131072u);

  prep_kernel<<<dim3(4096), dim3(256), 0, stream>>>(
      enc_whh, mdec_whh, pdec_whh, mdec_wih, pdec_wih, h0e, h0m, h0p,
      wfrag_enc, wfrag_m, wfrag_p, wfrag_gi, he_st, hm_st, hp_st, hpsum, flags);

  // encoder slice 0 only
  rec_kernel<<<dim3(192), dim3(256), 0, stream>>>(
      seq, dpad, enc_wih, enc_bih, enc_bhh, mdec_bhh, pdec_bhh,
      mlin_w, mlin_b, wfrag_enc, wfrag_m, wfrag_p, he_st, hm_st, hp_st,
      he_buf, gi_buf, hpsum, out, xchg, flags, -1, 0, SL);
  gi_kernel<<<dim3(SL*4), dim3(256), 0, stream>>>(he_buf, wfrag_gi, mdec_bih, pdec_bih, gi_buf);

  for (int s=0; s<S; ++s){
    const int enc_s = (s+1 < S) ? (s+1) : -1;
    rec_kernel<<<dim3(192), dim3(256), 0, stream>>>(
        seq, dpad, enc_wih, enc_bih, enc_bhh, mdec_bhh, pdec_bhh,
        mlin_w, mlin_b, wfrag_enc, wfrag_m, wfrag_p, he_st, hm_st, hp_st,
        he_buf, gi_buf, hpsum, out, xchg, flags, s, enc_s, SL);
    if (enc_s >= 0)
      gi_kernel<<<dim3(SL*4), dim3(256), 0, stream>>>(he_buf, wfrag_gi, mdec_bih, pdec_bih, gi_buf);
  }

  pred_kernel<<<dim3(64), dim3(256), 0, stream>>>(hpsum, plin_w, plin_b, out);
}

// Round 11
// 3614.620 us; speedup vs baseline: 1.1693x; 1.1693x over previous
//
#include <hip/hip_runtime.h>
#include <hip/hip_fp16.h>

typedef _Float16 f16;
typedef _Float16 f16x8 __attribute__((ext_vector_type(8)));
typedef _Float16 f16x4 __attribute__((ext_vector_type(4)));
typedef float    f32x4 __attribute__((ext_vector_type(4)));

#define TT 512
#define BB 256
#define HH 256

// ---- workspace byte offsets ----
#define O_WFRAG_ENC 0u
#define O_WFRAG_M   393216u
#define O_WFRAG_P   786432u
#define O_WFRAG_GI  1179648u
#define O_HE_ST     1966080u
#define O_HM_ST     2097152u
#define O_HP_ST     2228224u
#define O_HPSUM     2359296u
#define O_DYN       2621440u
#define DYN_PER_STEP 917504u   // he_buf 131072 + gi_buf 786432 per step

__device__ __forceinline__ float sigf(float x){ return 1.0f/(1.0f+__expf(-x)); }
__device__ __forceinline__ float tanh_(float x){
  float xc = fminf(fmaxf(x,-15.f),15.f);
  float e  = __expf(2.f*xc);
  return (e-1.f)/(e+1.f);
}
// XOR-swizzled element index into a [16][256] f16 tile (16B granules ^ row&7)
__device__ __forceinline__ int hswz(int row, int j){
  return row*256 + ((((j>>3) ^ (row&7)))<<3) + (j&7);
}
// async global->LDS, 16B per lane (dest = wave-uniform base + lane*16)
__device__ __forceinline__ void gload_lds16(const void* g, void* l){
  __builtin_amdgcn_global_load_lds(
      (const __attribute__((address_space(1))) unsigned int*)g,
      (__attribute__((address_space(3))) unsigned int*)l, 16, 0, 0);
}
// scheduling fences (rule #18: sched_barrier(0) is the fence that holds)
#define SB()        __builtin_amdgcn_sched_barrier(0)
#define LGKM0_SB()  do{ asm volatile("s_waitcnt lgkmcnt(0)" ::: "memory"); SB(); }while(0)
#define WAITV6_SB() do{ asm volatile("s_waitcnt vmcnt(6)"   ::: "memory"); SB(); }while(0)

// =====================================================================
// PREP: weights -> f16 fragment buffers (rec: ks-major chunks), states
// =====================================================================
__global__ void prep_kernel(
    const float* __restrict__ enc_whh, const float* __restrict__ mdec_whh,
    const float* __restrict__ pdec_whh, const float* __restrict__ mdec_wih,
    const float* __restrict__ pdec_wih,
    const float* __restrict__ h0e, const float* __restrict__ h0m, const float* __restrict__ h0p,
    f16* __restrict__ wfrag_enc, f16* __restrict__ wfrag_m, f16* __restrict__ wfrag_p,
    f16* __restrict__ wfrag_gi,
    f16* __restrict__ he_st, f16* __restrict__ hm_st, f16* __restrict__ hp_st,
    float* __restrict__ hpsum)
{
  int idx = blockIdx.x*256 + threadIdx.x;
  const int NW = 8*48*64*8; // 196608 per recurrence buffer (ks-major chunks)
  if (idx < 3*NW){
    int b = idx / NW, e = idx % NW;
    int jj = e & 7, l = (e>>3)&63, c = e>>9;    // c in [0,384)
    int ks = c / 48, rem = c % 48;
    int w = rem / 3, g = rem % 3;
    int row = g*256 + w*16 + (l&15);
    int col = ks*32 + (l>>4)*8 + jj;
    const float* W = (b==0)?enc_whh:((b==1)?mdec_whh:pdec_whh);
    f16* D = (b==0)?wfrag_enc:((b==1)?wfrag_m:wfrag_p);
    D[e] = (f16)W[row*256+col];
    return;
  }
  idx -= 3*NW;
  const int NG = 96*8*64*8; // 393216
  if (idx < NG){
    int e = idx;
    int jj = e&7, l=(e>>3)&63, ks=(e>>9)&7, mt = e>>12;
    int row = mt*16 + (l&15);
    int col = ks*32 + (l>>4)*8 + jj;
    float v = (row < 768) ? mdec_wih[row*256+col] : pdec_wih[(row-768)*256+col];
    wfrag_gi[e] = (f16)v;
    return;
  }
  idx -= NG;
  if (idx < 65536){
    he_st[idx] = (f16)h0e[idx];
    hm_st[idx] = (f16)h0m[idx];
    hp_st[idx] = (f16)h0p[idx];
    hpsum[idx] = 0.f;
  }
}

// =====================================================================
// Recurrence core. MODE 0=encoder, 1=mask-dec, 2=pred-dec.
// 512 threads (8 waves) per (rec, 16-row batch tile); NO cross-WG sync.
// W_hh is STREAMED L2->LDS each step: 8 ks-chunks of 48 KB, double-
// buffered; each wave stages only its own 6 fragments (6 KB) of each
// chunk. Per-iteration pinned schedule:
//   lgkmcnt(0)+SB  -> prior ds_reads done, safe to overwrite their buffer
//   prefetch(k+1)  -> 6 x global_load_lds
//   SB             -> prefetch block pinned in issue order
//   vmcnt(6)+SB    -> chunk k DMA complete (newest 6 = chunk k+1 in flight)
//   ds_read + MFMA on chunk k
// One __syncthreads per step (h double-buffer) drains the queue so the
// counts stay deterministic. Working set ~100 VGPR -> no spill.
// =====================================================================
template<int MODE>
__device__ __forceinline__ void gru_run(
  int bt, int slice, int SL,
  const f16* __restrict__ wfrag,
  const float* __restrict__ bih, const float* __restrict__ bhh,
  const float* __restrict__ enc_wih,
  const float* __restrict__ seq, const float* __restrict__ dpad,
  const f16* __restrict__ gi_src,       // pre-offset for (bt, rec); bih folded in
  f16* __restrict__ h_state,
  f16* __restrict__ he_buf,
  const float* __restrict__ mlin_w, const float* __restrict__ mlin_b,
  float* __restrict__ out_mask,
  float* __restrict__ hpsum,
  unsigned char* smem)
{
  const int tid = threadIdx.x;       // 512
  const int lane = tid & 63;
  const int wid  = tid >> 6;         // 0..7
  const int l15  = lane & 15;
  const int lhi  = lane >> 4;
  const int bi0  = lhi*4;
  const int b0   = bt*16;
  const int w0   = wid*2;            // first owned j-block

  f16* wbuf = (f16*)smem;                          // [2][24576] chunk dbuf (96 KB)
  f16* hbuf = (f16*)(smem + 98304);                // [2][4096] swizzled h (16 KB)
  float* xb   = (float*)(smem + 98304 + 16384);    // [2][16] (enc)
  float* mred = xb + 32;                           // [2][8 waves][16 rows]

  // ---- per-lane biases (dec: bih folded into gi by gi_kernel)
  float cr[2], cz[2], cnh[2], cni[2];
  float wr_[2], wz_[2], wn_[2], mw[2];
  #pragma unroll
  for (int q=0;q<2;++q){
    const int j = (w0+q)*16 + l15;
    if (MODE==0){
      cr[q]  = bih[j]     + bhh[j];
      cz[q]  = bih[256+j] + bhh[256+j];
      cnh[q] = bhh[512+j];
      cni[q] = bih[512+j];
      wr_[q]=enc_wih[j]; wz_[q]=enc_wih[256+j]; wn_[q]=enc_wih[512+j];
    } else {
      cr[q]  = bhh[j];
      cz[q]  = bhh[256+j];
      cnh[q] = bhh[512+j];
      cni[q] = 0.f;
    }
    if (MODE==1){ mw[q]=mlin_w[j]; }
  }
  // ---- initial h state -> hbuf[0]
  #pragma unroll
  for (int q=0;q<2;++q){
    const int j = (w0+q)*16 + l15;
    #pragma unroll
    for (int r=0;r<4;++r)
      hbuf[hswz(bi0+r, j)] = h_state[(size_t)(b0+bi0+r)*256 + j];
  }
  if (MODE==0 && tid<16){
    const int t = slice*SL;
    xb[tid] = (t==0) ? dpad[b0+tid] : seq[(size_t)(t-1)*BB + b0 + tid];
  }
  // ---- bootstrap: stage chunk 0 (own 6 fragments) into buf0
  #pragma unroll
  for (int q=0;q<2;++q)
    #pragma unroll
    for (int g=0;g<3;++g){
      const int fo = ((w0+q)*3+g)*1024;   // fragment byte offset in chunk
      gload_lds16((const char*)wfrag + fo + (lane<<4), (char*)wbuf + fo);
    }
  __syncthreads();   // drains bootstrap loads too

  float psum[2][4];
  if (MODE==2){
    #pragma unroll
    for (int q=0;q<2;++q)
      #pragma unroll
      for (int r=0;r<4;++r) psum[q][r]=0.f;
  }

  for (int ts=0; ts<SL; ++ts){
    const int cur = ts & 1;
    f16* hc = hbuf + cur*4096;
    f16* hn = hbuf + (cur^1)*4096;

    // gi loads for THIS step / x prefetch (enc); pinned at step top by SBs below
    f16x4 gv[2][3];
    if (MODE!=0){
      const f16* gts = gi_src + (size_t)ts*393216u;
      #pragma unroll
      for (int q=0;q<2;++q)
        #pragma unroll
        for (int g=0;g<3;++g)
          gv[q][g] = *(const f16x4*)(gts + ((size_t)(g*256 + (w0+q)*16 + l15))*16 + bi0);
    } else if (tid<16 && ts+1<SL){
      xb[(cur^1)*16 + tid] = seq[(size_t)(slice*SL + ts)*BB + b0 + tid];
    }
    // mask output for previous step (other mred parity; race-free)
    if (MODE==1 && tid<16 && ts>0){
      float v = mlin_b[0];
      #pragma unroll
      for (int w=0;w<8;++w) v += mred[(cur^1)*128 + w*16 + tid];
      out_mask[(size_t)(slice*SL + ts-1)*BB + b0 + tid] = v;
    }

    // ---- streamed-MFMA phase: ks-outer, chunk double-buffer, pinned order
    f32x4 acc[2][3];
    #pragma unroll
    for (int q=0;q<2;++q){
      acc[q][0] = (f32x4){cr[q],cr[q],cr[q],cr[q]};
      acc[q][1] = (f32x4){cz[q],cz[q],cz[q],cz[q]};
      acc[q][2] = (f32x4){cnh[q],cnh[q],cnh[q],cnh[q]};
    }
    #pragma unroll
    for (int k=0;k<8;++k){
      LGKM0_SB();   // prior ds_reads complete -> safe to overwrite their buffer
      // prefetch next chunk (k<7) or next step's chunk 0 (k==7)
      {
        const int nk = (k<7) ? (k+1) : 0;
        const char* src = (const char*)wfrag + (size_t)nk*49152u;
        char* dst = (char*)wbuf + (nk&1)*49152;
        #pragma unroll
        for (int q=0;q<2;++q)
          #pragma unroll
          for (int g=0;g<3;++g){
            const int fo = ((w0+q)*3+g)*1024;
            gload_lds16(src + fo + (lane<<4), dst + fo);
          }
      }
      SB();         // prefetch block pinned: issue order across iterations fixed
      if (k>0) WAITV6_SB();   // chunk k complete (newest 6 = chunk k+1 in flight)
      // k==0: chunk 0 drained by the step-end / bootstrap barrier

      const f16* wb = wbuf + (k&1)*24576;
      const f16x8 a = *(const f16x8*)(hc + l15*256 + ((((k*4+lhi) ^ (l15&7)))<<3));
      #pragma unroll
      for (int q=0;q<2;++q)
        #pragma unroll
        for (int g=0;g<3;++g){
          const f16x8 b = *(const f16x8*)(wb + (((w0+q)*3+g)*64 + lane)*8);
          acc[q][g] = __builtin_amdgcn_mfma_f32_16x16x32_f16(a, b, acc[q][g], 0,0,0);
        }
    }

    // ---- gate phase
    float mpart[4] = {0.f,0.f,0.f,0.f};
    #pragma unroll
    for (int q=0;q<2;++q){
      const int j = (w0+q)*16 + l15;
      float gir[4], giz[4], gin[4];
      if (MODE==0){
        #pragma unroll
        for (int r=0;r<4;++r){
          const float x = xb[cur*16 + bi0 + r];
          gir[r]=x*wr_[q]; giz[r]=x*wz_[q]; gin[r]=x*wn_[q] + cni[q];
        }
      } else {
        #pragma unroll
        for (int r=0;r<4;++r){
          gir[r]=(float)gv[q][0][r]; giz[r]=(float)gv[q][1][r]; gin[r]=(float)gv[q][2][r];
        }
      }
      #pragma unroll
      for (int r=0;r<4;++r){
        const int sz = hswz(bi0+r, j);
        const float hprev = (float)hc[sz];
        const float rr = sigf(gir[r] + acc[q][0][r]);
        const float zz = sigf(giz[r] + acc[q][1][r]);
        const float nn = tanh_(gin[r] + rr*acc[q][2][r]);
        const float h  = (1.f-zz)*nn + zz*hprev;
        hn[sz] = (f16)h;
        if (MODE==0) he_buf[((size_t)ts*BB + (b0+bi0+r))*HH + j] = (f16)h;
        if (MODE==1) mpart[r] += h*mw[q];
        if (MODE==2) psum[q][r] += h;
      }
    }
    if (MODE==1){
      #pragma unroll
      for (int m=1;m<16;m<<=1){
        #pragma unroll
        for (int r=0;r<4;++r) mpart[r] += __shfl_xor(mpart[r], m, 64);
      }
      if (l15==0){
        #pragma unroll
        for (int r=0;r<4;++r) mred[cur*128 + wid*16 + bi0 + r] = mpart[r];
      }
    }
    __syncthreads();   // h dbuf swap; also drains load queue (deterministic counts)
  }

  // final mask row
  if (MODE==1 && tid<16){
    float v = mlin_b[0];
    #pragma unroll
    for (int w=0;w<8;++w) v += mred[((SL-1)&1)*128 + w*16 + tid];
    out_mask[(size_t)(slice*SL + SL-1)*BB + b0 + tid] = v;
  }
  // h state writeback
  {
    const f16* hf = hbuf + (SL&1)*4096;
    #pragma unroll
    for (int q=0;q<2;++q){
      const int j = (w0+q)*16 + l15;
      #pragma unroll
      for (int r=0;r<4;++r)
        h_state[(size_t)(b0+bi0+r)*256 + j] = hf[hswz(bi0+r, j)];
    }
  }
  if (MODE==2){
    #pragma unroll
    for (int q=0;q<2;++q){
      const int j = (w0+q)*16 + l15;
      #pragma unroll
      for (int r=0;r<4;++r){
        const size_t idx = (size_t)(b0+bi0+r)*256 + j;
        hpsum[idx] = hpsum[idx] + psum[q][r];
      }
    }
  }
}

// 48 blocks: 0..15 mdec bt, 16..31 pdec bt, 32..47 enc bt.
__global__ __launch_bounds__(512) void rec_kernel(
  const float* __restrict__ seq, const float* __restrict__ dpad,
  const float* __restrict__ enc_wih, const float* __restrict__ enc_bih, const float* __restrict__ enc_bhh,
  const float* __restrict__ mdec_bhh, const float* __restrict__ pdec_bhh,
  const float* __restrict__ mlin_w, const float* __restrict__ mlin_b,
  const f16* __restrict__ wfrag_enc, const f16* __restrict__ wfrag_m, const f16* __restrict__ wfrag_p,
  f16* __restrict__ he_st, f16* __restrict__ hm_st, f16* __restrict__ hp_st,
  f16* __restrict__ he_buf, const f16* __restrict__ gi_buf,
  float* __restrict__ hpsum, float* __restrict__ out_mask,
  int dec_slice, int enc_slice, int SL)
{
  __shared__ __align__(16) unsigned char smem[98304 + 16384 + 128 + 1024 + 256];
  const int pp = blockIdx.x;
  if (pp < 16){
    if (dec_slice < 0) return;
    const int bt = pp;
    gru_run<1>(bt, dec_slice, SL, wfrag_m, nullptr, mdec_bhh, nullptr, nullptr, nullptr,
               gi_buf + (size_t)bt*1536*16, hm_st, nullptr, mlin_w, mlin_b, out_mask, nullptr, smem);
  } else if (pp < 32){
    if (dec_slice < 0) return;
    const int bt = pp - 16;
    gru_run<2>(bt, dec_slice, SL, wfrag_p, nullptr, pdec_bhh, nullptr, nullptr, nullptr,
               gi_buf + ((size_t)bt*1536 + 768)*16, hp_st, nullptr, nullptr, nullptr, nullptr, hpsum, smem);
  } else {
    if (enc_slice < 0) return;
    const int bt = pp - 32;
    gru_run<0>(bt, enc_slice, SL, wfrag_enc, enc_bih, enc_bhh, enc_wih, seq, dpad,
               nullptr, he_st, he_buf, nullptr, nullptr, nullptr, nullptr, smem);
  }
}

// =====================================================================
// GI: gi[t][b][n] = he[t][b][:] . w_ih_cat[n][:] + bih_cat[n]
// =====================================================================
__global__ __launch_bounds__(256,4) void gi_kernel(
  const f16* __restrict__ he_buf, const f16* __restrict__ wfrag_gi,
  const float* __restrict__ mdec_bih, const float* __restrict__ pdec_bih,
  f16* __restrict__ gi_buf)
{
  const int ts = blockIdx.x >> 2;
  const int bq = blockIdx.x & 3;
  const int tid = threadIdx.x, lane = tid&63, wid = tid>>6;
  const int l15 = lane&15, lhi = lane>>4;
  __shared__ f16 het[64*264];
  {
    const uint4* src = (const uint4*)(he_buf + ((size_t)ts*BB + bq*64)*HH);
    uint4* dst = (uint4*)het;
    #pragma unroll
    for (int k=0;k<8;++k){
      const int i = tid + k*256;
      dst[(i>>5)*33 + (i&31)] = src[i];
    }
  }
  __syncthreads();
  for (int mi=0; mi<24; ++mi){
    const int mt = wid*24 + mi;
    const int row0 = mt*16 + lhi*4;
    float bb[4];
    #pragma unroll
    for (int r=0;r<4;++r){
      const int rw = row0 + r;
      bb[r] = (rw < 768) ? mdec_bih[rw] : pdec_bih[rw-768];
    }
    f32x4 acc[4] = {{0,0,0,0},{0,0,0,0},{0,0,0,0},{0,0,0,0}};
    #pragma unroll
    for (int ks=0;ks<8;++ks){
      const f16x8 a = *(const f16x8*)(wfrag_gi + ((size_t)(mt*8+ks)*64 + lane)*8);
      #pragma unroll
      for (int bt=0;bt<4;++bt){
        const f16x8 b = *(const f16x8*)(het + (bt*16+l15)*264 + ks*32 + lhi*8);
        acc[bt] = __builtin_amdgcn_mfma_f32_16x16x32_f16(a, b, acc[bt], 0,0,0);
      }
    }
    #pragma unroll
    for (int bt=0;bt<4;++bt){
      const int btg = bq*4 + bt;
      const size_t base = (((size_t)ts*16 + btg)*1536 + (size_t)mt*16 + lhi*4)*16 + l15;
      #pragma unroll
      for (int r=0;r<4;++r) gi_buf[base + (size_t)r*16] = (f16)(acc[bt][r] + bb[r]);
    }
  }
}

// =====================================================================
// PRED: pred[b][p] = (hpsum[b]/512) . plin_w[p] + plin_b[p]
// =====================================================================
__global__ __launch_bounds__(256,1) void pred_kernel(
  const float* __restrict__ hpsum, const float* __restrict__ plin_w,
  const float* __restrict__ plin_b, float* __restrict__ out)
{
  __shared__ float hs[256];
  const int p = threadIdx.x;
  const float bias = plin_b[p];
  for (int bb=0; bb<4; ++bb){
    const int b = blockIdx.x*4 + bb;
    __syncthreads();
    hs[p] = hpsum[(size_t)b*256 + p];
    __syncthreads();
    float acc = 0.f;
    const float4* wrow = (const float4*)(plin_w + (size_t)p*256);
    #pragma unroll 4
    for (int k4=0;k4<64;++k4){
      const float4 w = wrow[k4];
      acc += hs[k4*4+0]*w.x + hs[k4*4+1]*w.y + hs[k4*4+2]*w.z + hs[k4*4+3]*w.w;
    }
    out[131072 + (size_t)b*256 + p] = acc*(1.f/512.f) + bias;
  }
}

// =====================================================================
extern "C" void kernel_launch(void* const* d_in, const int* in_sizes, int n_in,
                              void* d_out, int out_size, void* d_ws, size_t ws_size,
                              hipStream_t stream)
{
  const float* seq      = (const float*)d_in[0];
  const float* dpad     = (const float*)d_in[1];
  const float* h0e      = (const float*)d_in[2];
  const float* h0m      = (const float*)d_in[3];
  const float* h0p      = (const float*)d_in[4];
  const float* enc_wih  = (const float*)d_in[5];
  const float* enc_whh  = (const float*)d_in[6];
  const float* enc_bih  = (const float*)d_in[7];
  const float* enc_bhh  = (const float*)d_in[8];
  const float* mdec_wih = (const float*)d_in[9];
  const float* mdec_whh = (const float*)d_in[10];
  const float* mdec_bih = (const float*)d_in[11];
  const float* mdec_bhh = (const float*)d_in[12];
  const float* mlin_w   = (const float*)d_in[13];
  const float* mlin_b   = (const float*)d_in[14];
  const float* pdec_wih = (const float*)d_in[15];
  const float* pdec_whh = (const float*)d_in[16];
  const float* pdec_bih = (const float*)d_in[17];
  const float* pdec_bhh = (const float*)d_in[18];
  const float* plin_w   = (const float*)d_in[19];
  const float* plin_b   = (const float*)d_in[20];
  float* out = (float*)d_out;

  char* ws = (char*)d_ws;
  f16* wfrag_enc = (f16*)(ws + O_WFRAG_ENC);
  f16* wfrag_m   = (f16*)(ws + O_WFRAG_M);
  f16* wfrag_p   = (f16*)(ws + O_WFRAG_P);
  f16* wfrag_gi  = (f16*)(ws + O_WFRAG_GI);
  f16* he_st     = (f16*)(ws + O_HE_ST);
  f16* hm_st     = (f16*)(ws + O_HM_ST);
  f16* hp_st     = (f16*)(ws + O_HP_ST);
  float* hpsum   = (float*)(ws + O_HPSUM);

  int SL = 64;
  while (SL > 1 && (size_t)O_DYN + (size_t)SL*DYN_PER_STEP > ws_size) SL >>= 1;
  const int S = TT / SL;
  f16* he_buf = (f16*)(ws + O_DYN);
  f16* gi_buf = (f16*)(ws + O_DYN + (size_t)SL*131072u);

  prep_kernel<<<dim3(4096), dim3(256), 0, stream>>>(
      enc_whh, mdec_whh, pdec_whh, mdec_wih, pdec_wih, h0e, h0m, h0p,
      wfrag_enc, wfrag_m, wfrag_p, wfrag_gi, he_st, hm_st, hp_st, hpsum);

  // encoder slice 0 only
  rec_kernel<<<dim3(48), dim3(512), 0, stream>>>(
      seq, dpad, enc_wih, enc_bih, enc_bhh, mdec_bhh, pdec_bhh,
      mlin_w, mlin_b, wfrag_enc, wfrag_m, wfrag_p, he_st, hm_st, hp_st,
      he_buf, gi_buf, hpsum, out, -1, 0, SL);
  gi_kernel<<<dim3(SL*4), dim3(256), 0, stream>>>(he_buf, wfrag_gi, mdec_bih, pdec_bih, gi_buf);

  for (int s=0; s<S; ++s){
    const int enc_s = (s+1 < S) ? (s+1) : -1;
    rec_kernel<<<dim3(48), dim3(512), 0, stream>>>(
        seq, dpad, enc_wih, enc_bih, enc_bhh, mdec_bhh, pdec_bhh,
        mlin_w, mlin_b, wfrag_enc, wfrag_m, wfrag_p, he_st, hm_st, hp_st,
        he_buf, gi_buf, hpsum, out, s, enc_s, SL);
    if (enc_s >= 0)
      gi_kernel<<<dim3(SL*4), dim3(256), 0, stream>>>(he_buf, wfrag_gi, mdec_bih, pdec_bih, gi_buf);
  }

  pred_kernel<<<dim3(64), dim3(256), 0, stream>>>(hpsum, plin_w, plin_b, out);
}